// Round 1
// baseline (390.823 us; speedup 1.0000x reference)
//
#include <hip/hip_runtime.h>
#include <hip/hip_bf16.h>

// ---------------- problem constants ----------------
#define HW    4096      // H*W
#define CH    64        // C = G*T = 64
#define BB    8         // batch
#define TT    8         // time steps

// ws layout (in floats)
constexpr int OFF_SBUF  = 0;                 // 8*64*4096 = 2097152 floats
constexpr int OFF_WFRAG = 2097152;           // 32 frags * 64 lanes * 16B = 8192 floats
constexpr int OFF_WTIN  = OFF_WFRAG + 8192;  // 4096 floats (Wt_in[c][o])
constexpr int OFF_WTOUT = OFF_WTIN + 4096;   // 4096 floats (Wt_out[gt][o])
constexpr int OFF_WX    = OFF_WTOUT + 4096;  // 256
constexpr int OFF_BIAS  = OFF_WX + 256;      // 256
constexpr int OFF_WS    = OFF_BIAS + 256;    // 64

typedef __bf16 bf16x8 __attribute__((ext_vector_type(8)));
typedef float  floatx4 __attribute__((ext_vector_type(4)));

__device__ inline unsigned short f2bf(float f) {
    union { float f; unsigned u; } x; x.f = f;
    unsigned r = x.u + 0x7fffu + ((x.u >> 16) & 1u);   // RNE
    return (unsigned short)(r >> 16);
}

__device__ inline float fast_exp2(float x) {
#if __has_builtin(__builtin_amdgcn_exp2f)
    return __builtin_amdgcn_exp2f(x);
#else
    return __builtin_exp2f(x);
#endif
}
__device__ inline float fast_rcp(float x) {
#if __has_builtin(__builtin_amdgcn_rcpf)
    return __builtin_amdgcn_rcpf(x);
#else
    return 1.0f / x;
#endif
}
__device__ inline float fsig(float x) {
    // 1/(1+exp(-x)) = 1/(1+2^(-x*log2e))
    float e = fast_exp2(x * -1.44269504088896f);
    return fast_rcp(1.0f + e);
}
__device__ inline float ftanh(float x) {
    // tanh(x) = 1 - 2/(exp(2x)+1); exp(2x) = 2^(x*2*log2e)
    float e = fast_exp2(x * 2.88539008177793f);
    return 1.0f - 2.0f * fast_rcp(e + 1.0f);
}

// ---------------- prep: repack weights into d_ws ----------------
__global__ __launch_bounds__(256) void prep_kernel(
    const float* __restrict__ w_in, const float* __restrict__ w_ih,
    const float* __restrict__ w_hh, const float* __restrict__ b_ih,
    const float* __restrict__ b_hh, const float* __restrict__ w_s,
    const float* __restrict__ w_out, float* __restrict__ ws_f) {
    int tid = threadIdx.x;
    // w_hh -> B-fragment-ordered bf16. frag fi = nb*2+kc (nb 0..15 n-tile, kc 0..1 k-chunk)
    // entry e = fi*64 + lane; lane l holds w_hh[gate=(l&15)+16*nb][hid=kc*32+(l>>4)*8 + j], j=0..7
    uint4* wf = (uint4*)(ws_f + OFF_WFRAG);
    #pragma unroll
    for (int i = 0; i < 8; ++i) {
        int e  = tid + 256 * i;
        int l  = e & 63;
        int fi = e >> 6;
        int nb = fi >> 1, kc = fi & 1;
        int gate = (l & 15) + 16 * nb;
        int hid  = kc * 32 + (l >> 4) * 8;
        const float* src = w_hh + gate * 64 + hid;
        unsigned v[4];
        #pragma unroll
        for (int j = 0; j < 4; ++j) {
            unsigned lo = f2bf(src[2 * j]);
            unsigned hi = f2bf(src[2 * j + 1]);
            v[j] = lo | (hi << 16);
        }
        wf[e] = make_uint4(v[0], v[1], v[2], v[3]);
    }
    // transposed conv weights: Wt[c][o] = W[o][c]
    #pragma unroll
    for (int i = 0; i < 16; ++i) {
        int idx = tid + 256 * i;
        int o = idx & 63, c = idx >> 6;
        ws_f[OFF_WTIN  + idx] = w_in [o * 64 + c];
        ws_f[OFF_WTOUT + idx] = w_out[o * 64 + c];
    }
    ws_f[OFF_WX   + tid] = w_ih[tid];               // w_ih[:,0], flat 256
    ws_f[OFF_BIAS + tid] = b_ih[tid] + b_hh[tid];
    if (tid < 64) ws_f[OFF_WS + tid] = w_s[tid];
}

// ---------------- 1x1 conv (64ch -> 32 outputs per block-z) ----------------
// y[b][o][p] = sum_c Wt[c][o] * x[b][c][p] + bias[o]
__global__ __launch_bounds__(256) void conv_kernel(
    const float* __restrict__ x, const float* __restrict__ Wt,
    const float* __restrict__ bias, float* __restrict__ y) {
    int p  = blockIdx.x * 256 + threadIdx.x;
    int b  = blockIdx.y;
    int oh = blockIdx.z;           // 0/1 -> outputs [32*oh, 32*oh+32)
    const float* xb = x + b * CH * HW;
    float acc[32];
    #pragma unroll
    for (int j = 0; j < 32; ++j) acc[j] = 0.0f;
    #pragma unroll 4
    for (int c = 0; c < 64; ++c) {
        float hv = xb[c * HW + p];
        #pragma unroll
        for (int j = 0; j < 32; ++j)
            acc[j] = fmaf(Wt[c * 64 + oh * 32 + j], hv, acc[j]);
    }
    float* yb = y + b * CH * HW + oh * 32 * HW;
    #pragma unroll
    for (int j = 0; j < 32; ++j)
        yb[j * HW + p] = acc[j] + bias[oh * 32 + j];
}

// ---------------- fused per-pixel LSTM ----------------
// 1 wave = 16 sequences. gates(16x256) = h(16x64) @ w_hh^T via mfma 16x16x32 bf16.
// M=seq, N=gate. D layout: lane l, reg r -> seq=(l>>4)*4+r, gate=(l&15)+16*nb.
// A layout: lane l -> seq=l&15, hid=kc*32+(l>>4)*8+j.
__global__ __launch_bounds__(256) void lstm_kernel(
    const float* __restrict__ x,      // (B, 64, HW) from conv_in (lives in d_out)
    const float* __restrict__ ws_f,   // tables
    float* __restrict__ s_buf,        // (B, 64, HW) output s values
    const float* __restrict__ b_s_p) {
    __shared__ uint4 wfrag_lds[2048];                       // 32 KB
    __shared__ __align__(16) float x_lds[512];              // 2 KB: [t][seq_local]
    __shared__ __align__(16) unsigned short h_lds[4 * 16 * 72];  // 9 KB: per-wave 16 rows x 72 bf16 (144B rows)

    int tid = threadIdx.x;
    // stage w fragments (shared by all 4 waves)
    const uint4* wfg = (const uint4*)(ws_f + OFF_WFRAG);
    #pragma unroll
    for (int i = 0; i < 8; ++i) wfrag_lds[tid + 256 * i] = wfg[tid + 256 * i];
    // stage x for this block's 64 sequences (all 8 t)
    int n0b = blockIdx.x * 64;
    int bg  = n0b >> 12;           // b*8+g
    int p0  = n0b & 4095;
    #pragma unroll
    for (int i = 0; i < 2; ++i) {
        int idx = tid + 256 * i;
        int t = idx >> 6, sl = idx & 63;
        x_lds[t * 64 + sl] = x[(bg * 8 + t) * HW + p0 + sl];
    }
    // zero h state
    #pragma unroll
    for (int i = 0; i < 9; ++i) {
        int idx = tid + 256 * i;
        if (idx < 2304) ((unsigned*)h_lds)[idx] = 0u;
    }
    __syncthreads();

    int lane = tid & 63;
    int wv   = tid >> 6;
    int s    = lane & 15;
    int q    = lane >> 4;

    // per-lane constant tables
    float wx_r[16], bs_r[16];
    #pragma unroll
    for (int nb = 0; nb < 16; ++nb) {
        int gate = s + 16 * nb;
        wx_r[nb] = ws_f[OFF_WX + gate];
        bs_r[nb] = ws_f[OFF_BIAS + gate];
    }
    float wsv_r[4];
    #pragma unroll
    for (int hb = 0; hb < 4; ++hb) wsv_r[hb] = ws_f[OFF_WS + s + 16 * hb];
    float bs = b_s_p[0];

    unsigned short* hrow = h_lds + wv * 16 * 72;
    int pw = (n0b + wv * 16) & 4095;
    float c_st[4][4];
    #pragma unroll
    for (int hb = 0; hb < 4; ++hb)
        #pragma unroll
        for (int r = 0; r < 4; ++r) c_st[hb][r] = 0.0f;

    for (int t = 0; t < TT; ++t) {
        floatx4 xv = *(const floatx4*)&x_lds[t * 64 + wv * 16 + q * 4];
        bf16x8 a0 = *(const bf16x8*)(hrow + s * 72 + q * 8);        // k = 0..31
        bf16x8 a1 = *(const bf16x8*)(hrow + s * 72 + q * 8 + 32);   // k = 32..63
        float sp[4] = {0.f, 0.f, 0.f, 0.f};
        #pragma unroll
        for (int hb = 0; hb < 4; ++hb) {
            floatx4 acc[4];
            #pragma unroll
            for (int gi = 0; gi < 4; ++gi) {
                int nb = hb + 4 * gi;
                floatx4 a;
                #pragma unroll
                for (int r = 0; r < 4; ++r)
                    a[r] = fmaf(xv[r], wx_r[nb], bs_r[nb]);   // x*w_x + bias as C init
                bf16x8 bfr0 = *(const bf16x8*)&wfrag_lds[(nb * 2 + 0) * 64 + lane];
                bf16x8 bfr1 = *(const bf16x8*)&wfrag_lds[(nb * 2 + 1) * 64 + lane];
                a = __builtin_amdgcn_mfma_f32_16x16x32_bf16(a0, bfr0, a, 0, 0, 0);
                a = __builtin_amdgcn_mfma_f32_16x16x32_bf16(a1, bfr1, a, 0, 0, 0);
                acc[gi] = a;
            }
            float wsv = wsv_r[hb];
            #pragma unroll
            for (int r = 0; r < 4; ++r) {
                float ig = fsig(acc[0][r]);
                float fg = fsig(acc[1][r]);
                float gg = ftanh(acc[2][r]);
                float og = fsig(acc[3][r]);
                float c  = fmaf(fg, c_st[hb][r], ig * gg);
                c_st[hb][r] = c;
                float hn = og * ftanh(c);
                sp[r] = fmaf(hn, wsv, sp[r]);
                hrow[(q * 4 + r) * 72 + s + 16 * hb] = f2bf(hn);   // state for t+1
            }
        }
        // reduce s partials over the 16 lanes of this quarter's seq group
        #pragma unroll
        for (int m = 1; m < 16; m <<= 1) {
            sp[0] += __shfl_xor(sp[0], m, 64);
            sp[1] += __shfl_xor(sp[1], m, 64);
            sp[2] += __shfl_xor(sp[2], m, 64);
            sp[3] += __shfl_xor(sp[3], m, 64);
        }
        if (s == 0) {
            floatx4 o4 = {sp[0] + bs, sp[1] + bs, sp[2] + bs, sp[3] + bs};
            *(floatx4*)&s_buf[(bg * 8 + t) * HW + pw + q * 4] = o4;
        }
    }
}

extern "C" void kernel_launch(void* const* d_in, const int* in_sizes, int n_in,
                              void* d_out, int out_size, void* d_ws, size_t ws_size,
                              hipStream_t stream) {
    const float* h     = (const float*)d_in[0];
    const float* w_in  = (const float*)d_in[1];
    const float* b_in  = (const float*)d_in[2];
    const float* w_ih  = (const float*)d_in[3];
    const float* w_hh  = (const float*)d_in[4];
    const float* b_ih  = (const float*)d_in[5];
    const float* b_hh  = (const float*)d_in[6];
    const float* w_s   = (const float*)d_in[7];
    const float* b_s   = (const float*)d_in[8];
    const float* w_out = (const float*)d_in[9];
    const float* b_out = (const float*)d_in[10];
    float* out = (float*)d_out;
    float* ws  = (float*)d_ws;

    prep_kernel<<<1, 256, 0, stream>>>(w_in, w_ih, w_hh, b_ih, b_hh, w_s, w_out, ws);
    // conv_in: h -> x, stored in d_out (reused as scratch; overwritten later)
    conv_kernel<<<dim3(16, BB, 2), 256, 0, stream>>>(h, ws + OFF_WTIN, b_in, out);
    // fused LSTM: x (d_out) -> s_buf (ws)
    lstm_kernel<<<4096, 256, 0, stream>>>(out, ws, ws + OFF_SBUF, b_s);
    // conv_out: s_buf -> d_out
    conv_kernel<<<dim3(16, BB, 2), 256, 0, stream>>>(ws + OFF_SBUF, ws + OFF_WTOUT, b_out, out);
}